// Round 1
// baseline (314.922 us; speedup 1.0000x reference)
//
#include <hip/hip_runtime.h>

typedef _Float16 f16;
typedef _Float16 f16x8 __attribute__((ext_vector_type(8)));
typedef float    f32x4 __attribute__((ext_vector_type(4)));

// async global->LDS, 16B per lane. LDS dest is wave-uniform base + lane*16,
// our per-lane pointers are constructed to match exactly that layout.
__device__ __forceinline__ void gld_lds16(const void* g, void* l) {
    __builtin_amdgcn_global_load_lds((__attribute__((address_space(1))) void*)g,
                                     (__attribute__((address_space(3))) void*)l,
                                     16, 0, 0);
}

// C = A * B^T (+causal variants). A: [M,K] row-major lda. B: [N,K] row-major ldb.
// C: [M,N] row-major ldc. M = gridDim.y*128, N = gridDim.x*128. K mult of 32.
// MODE 0: plain. MODE 1: skip block if j0 > i0 (scores; upper-tri never read).
// MODE 2: Keff = min(K, i0+128) (PV; P rows are zero beyond the diagonal).
template<typename OutT, int MODE>
__global__ void __launch_bounds__(256)
gemm_bt(const f16* __restrict__ A, const f16* __restrict__ B, OutT* __restrict__ C,
        int lda, int ldb, int ldc, int K, float scale,
        long sA, long sB, long sC)
{
    const int bz = blockIdx.z;
    A += (long)bz * sA;
    B += (long)bz * sB;
    C += (long)bz * sC;

    const int i0 = blockIdx.y * 128;   // row tile (M)
    const int j0 = blockIdx.x * 128;   // col tile (N)
    if (MODE == 1 && j0 > i0) return;
    int Keff = K;
    if (MODE == 2) Keff = min(K, i0 + 128);

    __shared__ f16 As[128 * 32] __attribute__((aligned(16)));
    __shared__ f16 Bs[128 * 32] __attribute__((aligned(16)));

    const int tid  = threadIdx.x;
    const int lane = tid & 63;
    const int wave = tid >> 6;
    const int row16 = lane & 15;
    const int quad  = lane >> 4;
    const int wr = (wave >> 1) * 64;   // wave row offset in tile
    const int wc = (wave & 1) * 64;    // wave col offset in tile

    // staging: thread stages 16B; 256 threads cover 64 rows x 32 cols per issue
    const int srow = tid >> 2;         // 0..63
    const int scol = (tid & 3) * 8;    // f16 col 0/8/16/24
    const f16* gA = A + (long)(i0 + srow) * lda + scol;
    const f16* gB = B + (long)(j0 + srow) * ldb + scol;
    f16* lA  = As + srow * 32 + scol;
    f16* lB  = Bs + srow * 32 + scol;
    f16* lA2 = lA + 64 * 32;
    f16* lB2 = lB + 64 * 32;

    f32x4 acc[4][4] = {};

    for (int k0 = 0; k0 < Keff; k0 += 32) {
        gld_lds16(gA + k0,                  lA);
        gld_lds16(gA + k0 + (long)64 * lda, lA2);
        gld_lds16(gB + k0,                  lB);
        gld_lds16(gB + k0 + (long)64 * ldb, lB2);
        __syncthreads();

        f16x8 af[4], bf[4];
        #pragma unroll
        for (int t = 0; t < 4; t++) {
            af[t] = *(const f16x8*)(As + (wr + t * 16 + row16) * 32 + quad * 8);
            bf[t] = *(const f16x8*)(Bs + (wc + t * 16 + row16) * 32 + quad * 8);
        }
        #pragma unroll
        for (int mt = 0; mt < 4; mt++)
            #pragma unroll
            for (int nt = 0; nt < 4; nt++)
                acc[mt][nt] = __builtin_amdgcn_mfma_f32_16x16x32_f16(
                    af[mt], bf[nt], acc[mt][nt], 0, 0, 0);
        __syncthreads();
    }

    // epilogue: C[row][col], col = lane&15, row = quad*4 + reg
    #pragma unroll
    for (int mt = 0; mt < 4; mt++) {
        const int r0 = i0 + wr + mt * 16 + quad * 4;
        #pragma unroll
        for (int nt = 0; nt < 4; nt++) {
            const int c = j0 + wc + nt * 16 + row16;
            #pragma unroll
            for (int r = 0; r < 4; r++)
                C[(long)(r0 + r) * ldc + c] = (OutT)(acc[mt][nt][r] * scale);
        }
    }
}

// in-place causal softmax over fp16 scores; one block per row, 256 thr x 8 cols
__global__ void __launch_bounds__(256)
softmax_causal(f16* __restrict__ Sc)
{
    const int S = 2048;
    const long rowg = blockIdx.x;
    const long b = rowg >> 11;
    const int  i = (int)(rowg & 2047);
    f16* row = Sc + ((b * S + i) * (long)S);

    const int tid = threadIdx.x;
    const int c0  = tid * 8;
    const int lane = tid & 63, wave = tid >> 6;

    f16x8 in = *(const f16x8*)(row + c0);
    float v[8];
    float m = -3.4e38f;
    #pragma unroll
    for (int j = 0; j < 8; j++) {
        const bool ok = (c0 + j) <= i;
        v[j] = ok ? (float)in[j] : -3.4e38f;
        m = fmaxf(m, v[j]);
    }
    #pragma unroll
    for (int off = 32; off > 0; off >>= 1)
        m = fmaxf(m, __shfl_down(m, off, 64));
    __shared__ float redm[4];
    if (lane == 0) redm[wave] = m;
    __syncthreads();
    const float m0 = fmaxf(fmaxf(redm[0], redm[1]), fmaxf(redm[2], redm[3]));

    float e[8];
    float s = 0.f;
    #pragma unroll
    for (int j = 0; j < 8; j++) {
        const bool ok = (c0 + j) <= i;
        e[j] = ok ? __expf(v[j] - m0) : 0.f;
        s += e[j];
    }
    #pragma unroll
    for (int off = 32; off > 0; off >>= 1)
        s += __shfl_down(s, off, 64);
    __shared__ float reds[4];
    if (lane == 0) reds[wave] = s;
    __syncthreads();
    const float inv = 1.f / (reds[0] + reds[1] + reds[2] + reds[3]);

    f16x8 o;
    #pragma unroll
    for (int j = 0; j < 8; j++) o[j] = (f16)(e[j] * inv);
    *(f16x8*)(row + c0) = o;
}

__global__ void __launch_bounds__(256)
f32_to_f16(const float* __restrict__ src, f16* __restrict__ dst, long n)
{
    const long i = ((long)blockIdx.x * 256 + threadIdx.x) * 8;
    if (i >= n) return;
    f32x4 a = *(const f32x4*)(src + i);
    f32x4 b = *(const f32x4*)(src + i + 4);
    f16x8 o;
    o[0] = (f16)a[0]; o[1] = (f16)a[1]; o[2] = (f16)a[2]; o[3] = (f16)a[3];
    o[4] = (f16)b[0]; o[5] = (f16)b[1]; o[6] = (f16)b[2]; o[7] = (f16)b[3];
    *(f16x8*)(dst + i) = o;
}

extern "C" void kernel_launch(void* const* d_in, const int* in_sizes, int n_in,
                              void* d_out, int out_size, void* d_ws, size_t ws_size,
                              hipStream_t stream)
{
    (void)in_sizes; (void)n_in; (void)out_size; (void)ws_size;
    const float* x  = (const float*)d_in[0];
    const float* Wq = (const float*)d_in[1];
    const float* Wk = (const float*)d_in[2];
    const float* Wv = (const float*)d_in[3];
    float* out = (float*)d_out;

    const long NX = 4L * 2048 * 1024;   // 8388608 (B*S*E)
    const long NW = 1024L * 1024;

    char* p = (char*)d_ws;
    f16* xh  = (f16*)p; p += NX * 2;
    f16* wqh = (f16*)p; p += NW * 2;
    f16* wkh = (f16*)p; p += NW * 2;
    f16* wvh = (f16*)p; p += NW * 2;
    f16* Qh  = (f16*)p; p += NX * 2;
    f16* Kh  = (f16*)p; p += NX * 2;
    f16* Vt  = (f16*)p; p += NX * 2;              // [E=1024][B*S=8192]
    f16* Sc  = (f16*)p; p += 4L * 2048 * 2048 * 2; // scores -> P in place

    f32_to_f16<<<NX / 8 / 256, 256, 0, stream>>>(x,  xh,  NX);
    f32_to_f16<<<NW / 8 / 256, 256, 0, stream>>>(Wq, wqh, NW);
    f32_to_f16<<<NW / 8 / 256, 256, 0, stream>>>(Wk, wkh, NW);
    f32_to_f16<<<NW / 8 / 256, 256, 0, stream>>>(Wv, wvh, NW);

    // Q = x Wq^T : [8192,1024]
    gemm_bt<f16, 0><<<dim3(8, 64, 1), 256, 0, stream>>>(
        xh, wqh, Qh, 1024, 1024, 1024, 1024, 1.f, 0, 0, 0);
    // K = x Wk^T : [8192,1024]
    gemm_bt<f16, 0><<<dim3(8, 64, 1), 256, 0, stream>>>(
        xh, wkh, Kh, 1024, 1024, 1024, 1024, 1.f, 0, 0, 0);
    // V^T = Wv x^T : [1024, 8192]  (so PV's B-operand is K-contiguous)
    gemm_bt<f16, 0><<<dim3(64, 8, 1), 256, 0, stream>>>(
        wvh, xh, Vt, 1024, 1024, 8192, 1024, 1.f, 0, 0, 0);

    // Sc = Q K^T / 32 per batch : [2048,2048] x4, skip upper-tri blocks
    gemm_bt<f16, 1><<<dim3(16, 16, 4), 256, 0, stream>>>(
        Qh, Kh, Sc, 1024, 1024, 2048, 1024, 0.03125f,
        2048L * 1024, 2048L * 1024, 2048L * 2048);

    // causal softmax in place (writes zeros for j > i)
    softmax_causal<<<4 * 2048, 256, 0, stream>>>(Sc);

    // O = P V : A = P [2048,2048], B = Vt rows e, k = s (offset b*2048, ld 8192)
    gemm_bt<float, 2><<<dim3(8, 16, 4), 256, 0, stream>>>(
        Sc, Vt, out, 2048, 8192, 1024, 2048, 1.f,
        2048L * 2048, 2048L, 2048L * 1024);
}

// Round 2
// 310.631 us; speedup vs baseline: 1.0138x; 1.0138x over previous
//
#include <hip/hip_runtime.h>

typedef _Float16 f16;
typedef _Float16 f16x8 __attribute__((ext_vector_type(8)));
typedef float    f32x4 __attribute__((ext_vector_type(4)));

// async global->LDS, 16B per lane; LDS dest = wave-uniform base + lane*16,
// per-lane pointers below are constructed to match exactly that layout.
__device__ __forceinline__ void gld_lds16(const void* g, void* l) {
    __builtin_amdgcn_global_load_lds((__attribute__((address_space(1))) void*)g,
                                     (__attribute__((address_space(3))) void*)l,
                                     16, 0, 0);
}

// C = A * B^T. A: [M,K] row-major lda. B: [N,K] row-major ldb. C: [M,N] ldc.
// Tile: 128 M x 64 N x 32 K. grid.x = N/64, grid.y = M/128.
// MODE 0: plain. MODE 1: causal skip (tile dead if j0 >= i0+128).
// MODE 2: Keff = min(K, i0+128) (PV: P rows zero beyond diagonal).
template<typename OutT, int MODE>
__global__ void __launch_bounds__(256)
gemm_bt(const f16* __restrict__ A, const f16* __restrict__ B, OutT* __restrict__ C,
        int lda, int ldb, int ldc, int K, float scale,
        long sA, long sB, long sC)
{
    const int bz = blockIdx.z;
    A += (long)bz * sA;
    B += (long)bz * sB;
    C += (long)bz * sC;

    const int i0 = blockIdx.y * 128;   // row tile (M)
    const int j0 = blockIdx.x * 64;    // col tile (N)
    if (MODE == 1 && j0 >= i0 + 128) return;
    int Keff = K;
    if (MODE == 2) Keff = min(K, i0 + 128);

    __shared__ f16 As[128 * 32] __attribute__((aligned(16)));
    __shared__ f16 Bs[64 * 32]  __attribute__((aligned(16)));

    const int tid  = threadIdx.x;
    const int lane = tid & 63;
    const int wave = tid >> 6;
    const int row16 = lane & 15;
    const int quad  = lane >> 4;
    const int wr = (wave >> 1) * 64;   // wave row offset: 0 / 64
    const int wc = (wave & 1) * 32;    // wave col offset: 0 / 32

    // staging: each thread stages 16B; 256 threads cover 64 rows x 32 cols/issue
    const int srow = tid >> 2;         // 0..63
    const int scol = (tid & 3) * 8;    // f16 col 0/8/16/24
    const f16* gA = A + (long)(i0 + srow) * lda + scol;
    const f16* gB = B + (long)(j0 + srow) * ldb + scol;
    f16* lA  = As + srow * 32 + scol;
    f16* lA2 = lA + 64 * 32;
    f16* lB  = Bs + srow * 32 + scol;

    f32x4 acc[4][2] = {};

    for (int k0 = 0; k0 < Keff; k0 += 32) {
        gld_lds16(gA + k0,                  lA);
        gld_lds16(gA + k0 + (long)64 * lda, lA2);
        gld_lds16(gB + k0,                  lB);
        __syncthreads();

        f16x8 af[4], bf[2];
        #pragma unroll
        for (int t = 0; t < 4; t++)
            af[t] = *(const f16x8*)(As + (wr + t * 16 + row16) * 32 + quad * 8);
        #pragma unroll
        for (int t = 0; t < 2; t++)
            bf[t] = *(const f16x8*)(Bs + (wc + t * 16 + row16) * 32 + quad * 8);

        #pragma unroll
        for (int mt = 0; mt < 4; mt++)
            #pragma unroll
            for (int nt = 0; nt < 2; nt++)
                acc[mt][nt] = __builtin_amdgcn_mfma_f32_16x16x32_f16(
                    af[mt], bf[nt], acc[mt][nt], 0, 0, 0);
        __syncthreads();
    }

    // epilogue: C[row][col], col = lane&15, row = quad*4 + reg
    #pragma unroll
    for (int mt = 0; mt < 4; mt++) {
        const int r0 = i0 + wr + mt * 16 + quad * 4;
        #pragma unroll
        for (int nt = 0; nt < 2; nt++) {
            const int c = j0 + wc + nt * 16 + row16;
            #pragma unroll
            for (int r = 0; r < 4; r++)
                C[(long)(r0 + r) * ldc + c] = (OutT)(acc[mt][nt][r] * scale);
        }
    }
}

// in-place causal softmax over fp16 scores; one block per row, 256 thr x 8 cols
__global__ void __launch_bounds__(256)
softmax_causal(f16* __restrict__ Sc)
{
    const int S = 2048;
    const long rowg = blockIdx.x;
    const long b = rowg >> 11;
    const int  i = (int)(rowg & 2047);
    f16* row = Sc + ((b * S + i) * (long)S);

    const int tid = threadIdx.x;
    const int c0  = tid * 8;
    const int lane = tid & 63, wave = tid >> 6;

    f16x8 in = *(const f16x8*)(row + c0);
    float v[8];
    float m = -3.4e38f;
    #pragma unroll
    for (int j = 0; j < 8; j++) {
        const bool ok = (c0 + j) <= i;
        v[j] = ok ? (float)in[j] : -3.4e38f;
        m = fmaxf(m, v[j]);
    }
    #pragma unroll
    for (int off = 32; off > 0; off >>= 1)
        m = fmaxf(m, __shfl_down(m, off, 64));
    __shared__ float redm[4];
    if (lane == 0) redm[wave] = m;
    __syncthreads();
    const float m0 = fmaxf(fmaxf(redm[0], redm[1]), fmaxf(redm[2], redm[3]));

    float e[8];
    float s = 0.f;
    #pragma unroll
    for (int j = 0; j < 8; j++) {
        const bool ok = (c0 + j) <= i;
        e[j] = ok ? __expf(v[j] - m0) : 0.f;
        s += e[j];
    }
    #pragma unroll
    for (int off = 32; off > 0; off >>= 1)
        s += __shfl_down(s, off, 64);
    __shared__ float reds[4];
    if (lane == 0) reds[wave] = s;
    __syncthreads();
    const float inv = 1.f / (reds[0] + reds[1] + reds[2] + reds[3]);

    f16x8 o;
    #pragma unroll
    for (int j = 0; j < 8; j++) o[j] = (f16)(e[j] * inv);
    *(f16x8*)(row + c0) = o;
}

__global__ void __launch_bounds__(256)
f32_to_f16(const float* __restrict__ src, f16* __restrict__ dst, long n)
{
    const long i = ((long)blockIdx.x * 256 + threadIdx.x) * 8;
    if (i >= n) return;
    f32x4 a = *(const f32x4*)(src + i);
    f32x4 b = *(const f32x4*)(src + i + 4);
    f16x8 o;
    o[0] = (f16)a[0]; o[1] = (f16)a[1]; o[2] = (f16)a[2]; o[3] = (f16)a[3];
    o[4] = (f16)b[0]; o[5] = (f16)b[1]; o[6] = (f16)b[2]; o[7] = (f16)b[3];
    *(f16x8*)(dst + i) = o;
}

extern "C" void kernel_launch(void* const* d_in, const int* in_sizes, int n_in,
                              void* d_out, int out_size, void* d_ws, size_t ws_size,
                              hipStream_t stream)
{
    (void)in_sizes; (void)n_in; (void)out_size; (void)ws_size;
    const float* x  = (const float*)d_in[0];
    const float* Wq = (const float*)d_in[1];
    const float* Wk = (const float*)d_in[2];
    const float* Wv = (const float*)d_in[3];
    float* out = (float*)d_out;

    const long NX = 4L * 2048 * 1024;   // B*S*E = 8388608
    const long NW = 1024L * 1024;

    char* p = (char*)d_ws;
    f16* xh  = (f16*)p; p += NX * 2;
    f16* wqh = (f16*)p; p += NW * 2;
    f16* wkh = (f16*)p; p += NW * 2;
    f16* wvh = (f16*)p; p += NW * 2;
    f16* Qh  = (f16*)p; p += NX * 2;
    f16* Kh  = (f16*)p; p += NX * 2;
    f16* Vt  = (f16*)p; p += NX * 2;               // [E=1024][B*S=8192]
    f16* Sc  = (f16*)p; p += 4L * 2048 * 2048 * 2; // scores -> P in place

    f32_to_f16<<<NX / 8 / 256, 256, 0, stream>>>(x,  xh,  NX);
    f32_to_f16<<<NW / 8 / 256, 256, 0, stream>>>(Wq, wqh, NW);
    f32_to_f16<<<NW / 8 / 256, 256, 0, stream>>>(Wk, wkh, NW);
    f32_to_f16<<<NW / 8 / 256, 256, 0, stream>>>(Wv, wvh, NW);

    // Q = x Wq^T : [8192,1024], grid 16x64 = 1024 blocks
    gemm_bt<f16, 0><<<dim3(16, 64, 1), 256, 0, stream>>>(
        xh, wqh, Qh, 1024, 1024, 1024, 1024, 1.f, 0, 0, 0);
    // K = x Wk^T : [8192,1024]
    gemm_bt<f16, 0><<<dim3(16, 64, 1), 256, 0, stream>>>(
        xh, wkh, Kh, 1024, 1024, 1024, 1024, 1.f, 0, 0, 0);
    // V^T = Wv x^T : [1024, 8192], grid 128x8 = 1024 blocks
    gemm_bt<f16, 0><<<dim3(128, 8, 1), 256, 0, stream>>>(
        wvh, xh, Vt, 1024, 1024, 8192, 1024, 1.f, 0, 0, 0);

    // Sc = Q K^T / 32 per batch : [2048,2048] x4, upper-tri tiles skipped
    gemm_bt<f16, 1><<<dim3(32, 16, 4), 256, 0, stream>>>(
        Qh, Kh, Sc, 1024, 1024, 2048, 1024, 0.03125f,
        2048L * 1024, 2048L * 1024, 2048L * 2048);

    // causal softmax in place (writes zeros for j > i)
    softmax_causal<<<4 * 2048, 256, 0, stream>>>(Sc);

    // O = P V : A = P [2048,2048], B = Vt (k-contiguous rows), causal K-bound
    gemm_bt<float, 2><<<dim3(16, 16, 4), 256, 0, stream>>>(
        Sc, Vt, out, 2048, 8192, 1024, 2048, 1.f,
        2048L * 2048, 2048L, 2048L * 1024);
}

// Round 3
// 250.576 us; speedup vs baseline: 1.2568x; 1.2397x over previous
//
#include <hip/hip_runtime.h>

typedef _Float16 f16;
typedef _Float16 f16x8 __attribute__((ext_vector_type(8)));
typedef float    f32x4 __attribute__((ext_vector_type(4)));

// async global->LDS, 16B per lane; LDS dest = wave-uniform base + lane*16.
// Global source address is per-lane arbitrary (we exploit this for swizzling).
__device__ __forceinline__ void gld_lds16(const void* g, void* l) {
    __builtin_amdgcn_global_load_lds((__attribute__((address_space(1))) void*)g,
                                     (__attribute__((address_space(3))) void*)l,
                                     16, 0, 0);
}

// C = A * B^T. A: [M,K] row-major lda. B: [N,K] row-major ldb. C: [M,N] ldc.
// Tile: 128 M x 64 N x 64 K. grid.x = N/64, grid.y = M/128.
// LDS holds the tile with column-chunks XOR-swizzled per row:
//   LDS[row][cb*8..] = global chunk (cb ^ (row&7)), cb in 0..7 (8 f16 chunks)
// so MFMA fragment reads hit all 8 LDS bank-groups evenly.
// MODE 0: plain. MODE 1: causal skip (tile dead if j0 >= i0+128).
// MODE 2: Keff = min(K, i0+128) (PV: P rows zero beyond diagonal).
template<typename OutT, int MODE>
__global__ void __launch_bounds__(256)
gemm_bt(const f16* __restrict__ A, const f16* __restrict__ B, OutT* __restrict__ C,
        int lda, int ldb, int ldc, int K, float scale,
        long sA, long sB, long sC)
{
    const int bz = blockIdx.z;
    A += (long)bz * sA;
    B += (long)bz * sB;
    C += (long)bz * sC;

    const int i0 = blockIdx.y * 128;   // row tile (M)
    const int j0 = blockIdx.x * 64;    // col tile (N)
    if (MODE == 1 && j0 >= i0 + 128) return;
    int Keff = K;
    if (MODE == 2) Keff = min(K, i0 + 128);

    __shared__ f16 As[128 * 64] __attribute__((aligned(16)));
    __shared__ f16 Bs[64 * 64]  __attribute__((aligned(16)));

    const int tid  = threadIdx.x;
    const int lane = tid & 63;
    const int wave = tid >> 6;
    const int row16 = lane & 15;
    const int quad  = lane >> 4;
    const int swz   = row16 & 7;
    const int wr = (wave >> 1) * 64;   // wave row offset: 0 / 64
    const int wc = (wave & 1) * 32;    // wave col offset: 0 / 32

    // staging: thread stages 16B; 256 threads cover 32 rows x 64 cols/issue.
    // (srow + p*32)&7 == srow&7, so the col swizzle is issue-invariant.
    const int srow = tid >> 3;                       // 0..31
    const int scol = ((tid & 7) ^ (srow & 7)) * 8;   // swizzled global col
    const f16* gA = A + (long)(i0 + srow) * lda + scol;
    const f16* gB = B + (long)(j0 + srow) * ldb + scol;
    f16* lA = As + tid * 8;   // + p*32*64
    f16* lB = Bs + tid * 8;

    f32x4 acc[4][2] = {};

    for (int k0 = 0; k0 < Keff; k0 += 64) {
        gld_lds16(gA + k0,                  lA);
        gld_lds16(gA + k0 + (long)32 * lda, lA + 32 * 64);
        gld_lds16(gA + k0 + (long)64 * lda, lA + 64 * 64);
        gld_lds16(gA + k0 + (long)96 * lda, lA + 96 * 64);
        gld_lds16(gB + k0,                  lB);
        gld_lds16(gB + k0 + (long)32 * ldb, lB + 32 * 64);
        __syncthreads();

        #pragma unroll
        for (int kk = 0; kk < 2; kk++) {
            f16x8 af[4], bf[2];
            #pragma unroll
            for (int t = 0; t < 4; t++)
                af[t] = *(const f16x8*)(As + (wr + t * 16 + row16) * 64
                                           + (((kk * 4 + quad) ^ swz) * 8));
            #pragma unroll
            for (int t = 0; t < 2; t++)
                bf[t] = *(const f16x8*)(Bs + (wc + t * 16 + row16) * 64
                                           + (((kk * 4 + quad) ^ swz) * 8));
            #pragma unroll
            for (int mt = 0; mt < 4; mt++)
                #pragma unroll
                for (int nt = 0; nt < 2; nt++)
                    acc[mt][nt] = __builtin_amdgcn_mfma_f32_16x16x32_f16(
                        af[mt], bf[nt], acc[mt][nt], 0, 0, 0);
        }
        __syncthreads();
    }

    // epilogue: C[row][col], col = lane&15, row = quad*4 + reg
    #pragma unroll
    for (int mt = 0; mt < 4; mt++) {
        const int r0 = i0 + wr + mt * 16 + quad * 4;
        #pragma unroll
        for (int nt = 0; nt < 2; nt++) {
            const int c = j0 + wc + nt * 16 + row16;
            #pragma unroll
            for (int r = 0; r < 4; r++)
                C[(long)(r0 + r) * ldc + c] = (OutT)(acc[mt][nt][r] * scale);
        }
    }
}

// in-place causal softmax over fp16 scores; one block per row, 256 thr x 8 cols
__global__ void __launch_bounds__(256)
softmax_causal(f16* __restrict__ Sc)
{
    const int S = 2048;
    const long rowg = blockIdx.x;
    const long b = rowg >> 11;
    const int  i = (int)(rowg & 2047);
    f16* row = Sc + ((b * S + i) * (long)S);

    const int tid = threadIdx.x;
    const int c0  = tid * 8;
    const int lane = tid & 63, wave = tid >> 6;

    f16x8 in = *(const f16x8*)(row + c0);
    float v[8];
    float m = -3.4e38f;
    #pragma unroll
    for (int j = 0; j < 8; j++) {
        const bool ok = (c0 + j) <= i;
        v[j] = ok ? (float)in[j] : -3.4e38f;
        m = fmaxf(m, v[j]);
    }
    #pragma unroll
    for (int off = 32; off > 0; off >>= 1)
        m = fmaxf(m, __shfl_down(m, off, 64));
    __shared__ float redm[4];
    if (lane == 0) redm[wave] = m;
    __syncthreads();
    const float m0 = fmaxf(fmaxf(redm[0], redm[1]), fmaxf(redm[2], redm[3]));

    float e[8];
    float s = 0.f;
    #pragma unroll
    for (int j = 0; j < 8; j++) {
        const bool ok = (c0 + j) <= i;
        e[j] = ok ? __expf(v[j] - m0) : 0.f;
        s += e[j];
    }
    #pragma unroll
    for (int off = 32; off > 0; off >>= 1)
        s += __shfl_down(s, off, 64);
    __shared__ float reds[4];
    if (lane == 0) reds[wave] = s;
    __syncthreads();
    const float inv = 1.f / (reds[0] + reds[1] + reds[2] + reds[3]);

    f16x8 o;
    #pragma unroll
    for (int j = 0; j < 8; j++) o[j] = (f16)(e[j] * inv);
    *(f16x8*)(row + c0) = o;
}

// fused fp32->fp16 of x, Wq, Wk, Wv in one dispatch.
// blocks [0,4096): x -> xh ; [4096,4608): Wq ; [4608,5120): Wk ; [5120,5632): Wv
// Wq/Wk/Wv land contiguously in wh (so the QK projection sees one 2048-row B).
__global__ void __launch_bounds__(256)
convert_all(const float* __restrict__ x, const float* __restrict__ Wq,
            const float* __restrict__ Wk, const float* __restrict__ Wv,
            f16* __restrict__ xh, f16* __restrict__ wh)
{
    const long blk = blockIdx.x;
    const float* src;
    f16* dst;
    long base;
    if (blk < 4096)      { src = x;  dst = xh;                    base = blk * 2048; }
    else if (blk < 4608) { src = Wq; dst = wh;                    base = (blk - 4096) * 2048; }
    else if (blk < 5120) { src = Wk; dst = wh + 1024L * 1024;     base = (blk - 4608) * 2048; }
    else                 { src = Wv; dst = wh + 2L * 1024 * 1024; base = (blk - 5120) * 2048; }
    const long i = base + (long)threadIdx.x * 8;
    f32x4 a = *(const f32x4*)(src + i);
    f32x4 b = *(const f32x4*)(src + i + 4);
    f16x8 o;
    o[0] = (f16)a[0]; o[1] = (f16)a[1]; o[2] = (f16)a[2]; o[3] = (f16)a[3];
    o[4] = (f16)b[0]; o[5] = (f16)b[1]; o[6] = (f16)b[2]; o[7] = (f16)b[3];
    *(f16x8*)(dst + i) = o;
}

extern "C" void kernel_launch(void* const* d_in, const int* in_sizes, int n_in,
                              void* d_out, int out_size, void* d_ws, size_t ws_size,
                              hipStream_t stream)
{
    (void)in_sizes; (void)n_in; (void)out_size; (void)ws_size;
    const float* x  = (const float*)d_in[0];
    const float* Wq = (const float*)d_in[1];
    const float* Wk = (const float*)d_in[2];
    const float* Wv = (const float*)d_in[3];
    float* out = (float*)d_out;

    const long NX = 4L * 2048 * 1024;   // B*S*E = 8388608
    const long NW = 1024L * 1024;

    char* p = (char*)d_ws;
    f16* xh  = (f16*)p; p += NX * 2;
    f16* wh  = (f16*)p; p += 3 * NW * 2;            // Wq | Wk | Wv contiguous
    f16* QKh = (f16*)p; p += 2 * NX * 2;            // [8192][2048]: Q cols | K cols
    f16* Vt  = (f16*)p; p += NX * 2;                // [E=1024][B*S=8192]
    f16* Sc  = (f16*)p; p += 4L * 2048 * 2048 * 2;  // scores -> P in place
    f16* wvh = wh + 2L * NW;

    convert_all<<<5632, 256, 0, stream>>>(x, Wq, Wk, Wv, xh, wh);

    // QK = x [Wq;Wk]^T : [8192,2048], grid 32x64 = 2048 blocks
    gemm_bt<f16, 0><<<dim3(32, 64, 1), 256, 0, stream>>>(
        xh, wh, QKh, 1024, 1024, 2048, 1024, 1.f, 0, 0, 0);
    // V^T = Wv x^T : [1024, 8192], grid 128x8 = 1024 blocks
    gemm_bt<f16, 0><<<dim3(128, 8, 1), 256, 0, stream>>>(
        wvh, xh, Vt, 1024, 1024, 8192, 1024, 1.f, 0, 0, 0);

    // Sc = Q K^T / 32 per batch : [2048,2048] x4, upper-tri tiles skipped
    gemm_bt<f16, 1><<<dim3(32, 16, 4), 256, 0, stream>>>(
        QKh, QKh + 1024, Sc, 2048, 2048, 2048, 1024, 0.03125f,
        2048L * 2048, 2048L * 2048, 2048L * 2048);

    // causal softmax in place (writes zeros for j > i)
    softmax_causal<<<4 * 2048, 256, 0, stream>>>(Sc);

    // O = P V : A = P [2048,2048], B = Vt (k-contiguous rows), causal K-bound
    gemm_bt<float, 2><<<dim3(16, 16, 4), 256, 0, stream>>>(
        Sc, Vt, out, 2048, 8192, 1024, 2048, 1.f,
        2048L * 2048, 2048L, 2048L * 1024);
}